// Round 1
// baseline (49.056 us; speedup 1.0000x reference)
//
#include <hip/hip_runtime.h>
#include <hip/hip_bf16.h>

// ---------------------------------------------------------------------------
// MetricLearningLoss: total = sum_{i<j} f(||x_i-x_j||^2, same_label) / (2k)
//   f_same = -c*log(d2/Zs) + 0.5*d2/Zs ; f_diff = c*log(d2/Zo) - 0.5*d2/Zo
//   c = k/2-1 = 2047, Zs = 2k*sigma^2 = 327.68, Zo = 2k = 8192
// Strategy: bf16 MFMA gram (tiled, upper-tri blocks only) + fused epilogue.
// ---------------------------------------------------------------------------

#define KDIM  512
#define NROWS 4096
#define BM    128
#define BK    64
#define NT    (NROWS / BM)        // 32
#define NBLK  (NT * (NT + 1) / 2) // 528

typedef __bf16 bf16x8 __attribute__((ext_vector_type(8)));
typedef float  f32x4  __attribute__((ext_vector_type(4)));
typedef unsigned short u16x8 __attribute__((ext_vector_type(8)));

#define GLD_LDS16(gptr, lptr)                                                  \
    __builtin_amdgcn_global_load_lds(                                          \
        (const __attribute__((address_space(1))) void*)(gptr),                 \
        (__attribute__((address_space(3))) void*)(lptr), 16, 0, 0)

__device__ __forceinline__ unsigned short f2bf(float f) {
    unsigned int u = __float_as_uint(f);
    u = (u + 0x7FFFu + ((u >> 16) & 1u)) >> 16;   // RNE
    return (unsigned short)u;
}

// f32 -> bf16, stored with the st-style XOR swizzle pre-applied in GLOBAL
// memory: within each 64-col (128B) K-chunk, 16B slot c holds logical slot
// c ^ (row&7).  Then the main kernel's global_load_lds is a pure linear copy
// and the swizzled ds_read_b128 is bank-conflict-free (2-way max).
__global__ __launch_bounds__(256) void conv_swz_kernel(
        const float* __restrict__ x, unsigned short* __restrict__ xb) {
    int gid = blockIdx.x * 256 + threadIdx.x;     // one 8-elem group each
    int row = gid >> 6;                           // 64 groups per row
    int g   = gid & 63;
    int kt  = g >> 3;
    int c   = g & 7;
    int src = row * KDIM + kt * 64 + c * 8;
    int dst = row * KDIM + kt * 64 + ((c ^ (row & 7)) * 8);
    const float4* pf = reinterpret_cast<const float4*>(x + src);
    float4 f0 = pf[0], f1 = pf[1];
    u16x8 v;
    v[0] = f2bf(f0.x); v[1] = f2bf(f0.y); v[2] = f2bf(f0.z); v[3] = f2bf(f0.w);
    v[4] = f2bf(f1.x); v[5] = f2bf(f1.y); v[6] = f2bf(f1.z); v[7] = f2bf(f1.w);
    *reinterpret_cast<u16x8*>(xb + dst) = v;
}

// sq[row] = sum_k x[row][k]^2 in fp32 (exact inputs, not bf16)
__global__ __launch_bounds__(64) void sq_kernel(
        const float* __restrict__ x, float* __restrict__ sq) {
    int row  = blockIdx.x;
    int lane = threadIdx.x;
    const float4* p = reinterpret_cast<const float4*>(x + row * KDIM + lane * 8);
    float4 a = p[0], b = p[1];
    float s = a.x*a.x + a.y*a.y + a.z*a.z + a.w*a.w
            + b.x*b.x + b.y*b.y + b.z*b.z + b.w*b.w;
#pragma unroll
    for (int off = 32; off; off >>= 1) s += __shfl_down(s, off);
    if (lane == 0) sq[row] = s;
}

__global__ __launch_bounds__(256) void pair_loss_kernel(
        const unsigned short* __restrict__ xb,
        const float* __restrict__ sq,
        const int* __restrict__ labels,
        float* __restrict__ partials) {
    __shared__ __align__(16) unsigned short sA[2][BM * BK];  // 2 x 16 KB
    __shared__ __align__(16) unsigned short sB[2][BM * BK];  // 2 x 16 KB
    __shared__ float s_sqA[BM], s_sqB[BM];
    __shared__ int   s_labA[BM], s_labB[BM];
    __shared__ float s_red[4];

    const int tid = threadIdx.x;

    // linear block id -> upper-triangular (bi, bj), bi <= bj
    int t = blockIdx.x, bi = 0;
    while (t >= NT - bi) { t -= NT - bi; ++bi; }
    const int bj = bi + t;
    const int rowA0 = bi * BM, rowB0 = bj * BM;

    if (tid < BM) {
        s_sqA[tid]  = sq[rowA0 + tid];
        s_labA[tid] = labels[rowA0 + tid];
    } else {
        int r = tid - BM;
        s_sqB[r]  = sq[rowB0 + r];
        s_labB[r] = labels[rowB0 + r];
    }

    const int w  = tid >> 6, l = tid & 63;
    const int wr = w >> 1,  wc = w & 1;          // wave -> 64x64 quadrant
    const int lrow8 = l >> 3, lc8 = l & 7;       // staging coords
    const int lrow  = l & 15, lk  = l >> 4;      // MFMA fragment coords

    f32x4 acc[4][4];
#pragma unroll
    for (int m = 0; m < 4; ++m)
#pragma unroll
        for (int n = 0; n < 4; ++n)
            acc[m][n] = (f32x4){0.f, 0.f, 0.f, 0.f};

    auto stage = [&](int buf, int kt) {
#pragma unroll
        for (int i = 0; i < 4; ++i) {
            int q    = w * 4 + i;                 // 1 KB chunk (8 rows)
            int grow = q * 8 + lrow8;
            const unsigned short* gA =
                xb + (size_t)(rowA0 + grow) * KDIM + kt * BK + lc8 * 8;
            const unsigned short* gB =
                xb + (size_t)(rowB0 + grow) * KDIM + kt * BK + lc8 * 8;
            GLD_LDS16(gA, &sA[buf][q * 512]);
            GLD_LDS16(gB, &sB[buf][q * 512]);
        }
    };

    auto compute = [&](int buf) {
#pragma unroll
        for (int kk = 0; kk < 2; ++kk) {
            bf16x8 af[4], bf[4];
            int slot = (kk * 4 + lk) ^ (lrow & 7);  // XOR de-swizzle
#pragma unroll
            for (int m = 0; m < 4; ++m) {
                int r = wr * 64 + m * 16 + lrow;
                af[m] = *reinterpret_cast<const bf16x8*>(&sA[buf][r * BK + slot * 8]);
            }
#pragma unroll
            for (int n = 0; n < 4; ++n) {
                int r = wc * 64 + n * 16 + lrow;
                bf[n] = *reinterpret_cast<const bf16x8*>(&sB[buf][r * BK + slot * 8]);
            }
#pragma unroll
            for (int m = 0; m < 4; ++m)
#pragma unroll
                for (int n = 0; n < 4; ++n)
                    acc[m][n] = __builtin_amdgcn_mfma_f32_16x16x32_bf16(
                        af[m], bf[n], acc[m][n], 0, 0, 0);
        }
    };

    // minimal 2-phase prefetch pipeline
    stage(0, 0);
    __syncthreads();
    int cur = 0;
    for (int kt = 1; kt < KDIM / BK; ++kt) {
        stage(cur ^ 1, kt);
        compute(cur);
        __syncthreads();
        cur ^= 1;
    }
    compute(cur);

    // ---- fused epilogue --------------------------------------------------
    const float c_const = (float)NROWS * 0.5f - 1.0f;               // 2047
    const float inv_zs  = (float)(1.0 / (2.0 * 4096.0 * (0.2 * 0.2)));
    const float inv_zo  = (float)(1.0 / (2.0 * 4096.0));
    const float Cs      = __logf(inv_zs);                           // -log Zs
    const float Co      = __logf(inv_zo);                           // -log Zo

    float tsum = 0.0f;
#pragma unroll
    for (int n = 0; n < 4; ++n) {
        int   jloc = wc * 64 + n * 16 + lrow;
        int   gj   = rowB0 + jloc;
        float sqj  = s_sqB[jloc];
        int   labj = s_labB[jloc];
#pragma unroll
        for (int m = 0; m < 4; ++m) {
#pragma unroll
            for (int r = 0; r < 4; ++r) {
                int iloc = wr * 64 + m * 16 + lk * 4 + r;
                int gi   = rowA0 + iloc;
                if (gi < gj) {
                    float d2 = s_sqA[iloc] + sqj - 2.0f * acc[m][n][r];
                    d2 = fmaxf(d2, 1e-12f);           // NaN insurance
                    float lg   = __logf(d2);
                    bool  same = (s_labA[iloc] == labj);
                    float sc = same ? -c_const : c_const;
                    float Cx = same ? Cs : Co;
                    float Ix = same ? (0.5f * inv_zs) : (-0.5f * inv_zo);
                    tsum += sc * (lg + Cx) + d2 * Ix;
                }
            }
        }
    }
#pragma unroll
    for (int off = 32; off; off >>= 1) tsum += __shfl_down(tsum, off);
    if (l == 0) s_red[w] = tsum;
    __syncthreads();
    if (tid == 0)
        partials[blockIdx.x] = s_red[0] + s_red[1] + s_red[2] + s_red[3];
}

__global__ __launch_bounds__(256) void reduce_kernel(
        const float* __restrict__ partials, float* __restrict__ out) {
    __shared__ double s_red[4];
    int tid = threadIdx.x;
    double s = 0.0;
    for (int i = tid; i < NBLK; i += 256) s += (double)partials[i];
#pragma unroll
    for (int off = 32; off; off >>= 1) s += __shfl_down(s, off);
    if ((tid & 63) == 0) s_red[tid >> 6] = s;
    __syncthreads();
    if (tid == 0) {
        double tot = (s_red[0] + s_red[1] + s_red[2] + s_red[3])
                     / (2.0 * (double)NROWS);
        out[0] = (float)tot;
    }
}

extern "C" void kernel_launch(void* const* d_in, const int* in_sizes, int n_in,
                              void* d_out, int out_size, void* d_ws,
                              size_t ws_size, hipStream_t stream) {
    const float* x      = (const float*)d_in[0];
    const int*   labels = (const int*)d_in[1];
    float*       out    = (float*)d_out;

    char* ws = (char*)d_ws;
    unsigned short* xb = (unsigned short*)ws;                    // 4 MB bf16
    float* sq       = (float*)(ws + (size_t)NROWS * KDIM * 2);   // 16 KB
    float* partials = (float*)(ws + (size_t)NROWS * KDIM * 2 + NROWS * 4);

    conv_swz_kernel<<<NROWS * KDIM / 8 / 256, 256, 0, stream>>>(x, xb);
    sq_kernel<<<NROWS, 64, 0, stream>>>(x, sq);
    pair_loss_kernel<<<NBLK, 256, 0, stream>>>(xb, sq, labels, partials);
    reduce_kernel<<<1, 256, 0, stream>>>(partials, out);
}

// Round 2
// 40.046 us; speedup vs baseline: 1.2250x; 1.2250x over previous
//
#include <hip/hip_runtime.h>
#include <hip/hip_bf16.h>

// ---------------------------------------------------------------------------
// MetricLearningLoss: total = sum_{i<j} f(||x_i-x_j||^2, same_label) / (2k)
//   f_same = -c*log(d2/Zs) + 0.5*d2/Zs ; f_diff = c*log(d2/Zo) - 0.5*d2/Zo
// bf16 MFMA gram, upper-tri 128x128 tiles, BK=32, fused epilogue + last-block
// deterministic reduction.  2 kernels total.
// ---------------------------------------------------------------------------

#define KDIM  512
#define NROWS 4096
#define BM    128
#define BK    32
#define NT    (NROWS / BM)        // 32
#define NBLK  (NT * (NT + 1) / 2) // 528
#define NKT   (KDIM / BK)         // 16

typedef __bf16 bf16x8 __attribute__((ext_vector_type(8)));
typedef float  f32x4  __attribute__((ext_vector_type(4)));
typedef unsigned short u16x8 __attribute__((ext_vector_type(8)));

#define GLD_LDS16(gptr, lptr)                                                  \
    __builtin_amdgcn_global_load_lds(                                          \
        (const __attribute__((address_space(1))) void*)(gptr),                 \
        (__attribute__((address_space(3))) void*)(lptr), 16, 0, 0)

__device__ __forceinline__ unsigned short f2bf(float f) {
    unsigned int u = __float_as_uint(f);
    u = (u + 0x7FFFu + ((u >> 16) & 1u)) >> 16;   // RNE
    return (unsigned short)u;
}

// Fused: f32 -> bf16 convert with the XOR swizzle pre-applied in GLOBAL
// memory (within each 32-col = 64B K-chunk, 16B slot c' = c ^ ((row>>1)&3)
// holds logical slot c), row sum-of-squares in fp32, ticket zeroing.
// One wave per row (64 lanes x 8 f32).
__global__ __launch_bounds__(256) void prep_kernel(
        const float* __restrict__ x, unsigned short* __restrict__ xb,
        float* __restrict__ sq, unsigned int* __restrict__ ticket) {
    if (blockIdx.x == 0 && threadIdx.x == 0) *ticket = 0u;
    const int w = threadIdx.x >> 6, l = threadIdx.x & 63;
    const int row = blockIdx.x * 4 + w;
    const float4* pf = reinterpret_cast<const float4*>(x + row * KDIM + l * 8);
    float4 f0 = pf[0], f1 = pf[1];
    float s = f0.x*f0.x + f0.y*f0.y + f0.z*f0.z + f0.w*f0.w
            + f1.x*f1.x + f1.y*f1.y + f1.z*f1.z + f1.w*f1.w;
#pragma unroll
    for (int off = 32; off; off >>= 1) s += __shfl_down(s, off);
    if (l == 0) sq[row] = s;

    u16x8 v;
    v[0] = f2bf(f0.x); v[1] = f2bf(f0.y); v[2] = f2bf(f0.z); v[3] = f2bf(f0.w);
    v[4] = f2bf(f1.x); v[5] = f2bf(f1.y); v[6] = f2bf(f1.z); v[7] = f2bf(f1.w);
    const int kt = l >> 2;                       // 32-col chunk
    const int c  = l & 3;                        // logical 16B slot
    const int cp = c ^ ((row >> 1) & 3);         // physical (swizzled) slot
    *reinterpret_cast<u16x8*>(xb + row * KDIM + kt * 32 + cp * 8) = v;
}

template <bool DIAG>
__device__ __forceinline__ float epilogue_sum(
        const f32x4 (&acc)[4][4], const float* s_sqA, const float* s_sqB,
        const int* s_labA, const int* s_labB, int wr, int wc, int lrow, int lk) {
    const float c_const = (float)NROWS * 0.5f - 1.0f;               // 2047
    const float inv_zs  = (float)(1.0 / (2.0 * 4096.0 * (0.2 * 0.2)));
    const float inv_zo  = (float)(1.0 / (2.0 * 4096.0));
    const float Cs      = __logf(inv_zs);
    const float Co      = __logf(inv_zo);
    float tsum = 0.0f;
#pragma unroll
    for (int n = 0; n < 4; ++n) {
        const int   jloc = wc * 64 + n * 16 + lrow;
        const float sqj  = s_sqB[jloc];
        const int   labj = s_labB[jloc];
#pragma unroll
        for (int m = 0; m < 4; ++m) {
#pragma unroll
            for (int r = 0; r < 4; ++r) {
                const int iloc = wr * 64 + m * 16 + lk * 4 + r;
                if (!DIAG || (iloc < jloc)) {
                    float d2 = s_sqA[iloc] + sqj - 2.0f * acc[m][n][r];
                    d2 = fmaxf(d2, 1e-12f);
                    float lg   = __logf(d2);
                    bool  same = (s_labA[iloc] == labj);
                    float sc = same ? -c_const : c_const;
                    float Cx = same ? Cs : Co;
                    float Ix = same ? (0.5f * inv_zs) : (-0.5f * inv_zo);
                    tsum += sc * (lg + Cx) + d2 * Ix;
                }
            }
        }
    }
    return tsum;
}

__global__ __launch_bounds__(256, 3) void pair_loss_kernel(
        const unsigned short* __restrict__ xb,
        const float* __restrict__ sq,
        const int* __restrict__ labels,
        float* __restrict__ partials,
        unsigned int* __restrict__ ticket,
        float* __restrict__ out) {
    __shared__ __align__(16) unsigned short sA[2][BM * BK];  // 2 x 8 KB
    __shared__ __align__(16) unsigned short sB[2][BM * BK];  // 2 x 8 KB
    __shared__ float  s_sqA[BM], s_sqB[BM];
    __shared__ int    s_labA[BM], s_labB[BM];
    __shared__ float  s_red[4];
    __shared__ double s_redd[4];
    __shared__ bool   s_last;

    const int tid = threadIdx.x;

    // linear block id -> upper-triangular (bi, bj), bi <= bj
    int t = blockIdx.x, bi = 0;
    while (t >= NT - bi) { t -= NT - bi; ++bi; }
    const int bj = bi + t;
    const int rowA0 = bi * BM, rowB0 = bj * BM;
    const bool diag = (bi == bj);

    if (tid < BM) {
        s_sqA[tid]  = sq[rowA0 + tid];
        s_labA[tid] = labels[rowA0 + tid];
    } else {
        int r = tid - BM;
        s_sqB[r]  = sq[rowB0 + r];
        s_labB[r] = labels[rowB0 + r];
    }

    const int w  = tid >> 6, l = tid & 63;
    const int wr = w >> 1,  wc = w & 1;          // wave -> 64x64 quadrant
    const int lrow = l & 15, lk = l >> 4;        // MFMA fragment coords
    const int srow = l >> 2, sc16 = l & 3;       // staging coords (16 rows/KB)

    f32x4 acc[4][4];
#pragma unroll
    for (int m = 0; m < 4; ++m)
#pragma unroll
        for (int n = 0; n < 4; ++n)
            acc[m][n] = (f32x4){0.f, 0.f, 0.f, 0.f};

    // per-iter staging: 8 KB per tile = 8 x 1KB chunks (16 rows each);
    // each wave stages 2 chunks of A and 2 of B (4 global_load_lds x 16B).
    auto stage = [&](int buf, int kt) {
#pragma unroll
        for (int i = 0; i < 2; ++i) {
            const int q    = w * 2 + i;
            const int grow = q * 16 + srow;
            const unsigned short* gA =
                xb + (size_t)(rowA0 + grow) * KDIM + kt * BK + sc16 * 8;
            const unsigned short* gB =
                xb + (size_t)(rowB0 + grow) * KDIM + kt * BK + sc16 * 8;
            GLD_LDS16(gA, &sA[buf][q * 512]);
            GLD_LDS16(gB, &sB[buf][q * 512]);
        }
    };

    auto compute = [&](int buf) {
        bf16x8 af[4], bfr[4];
        const int slot = lk ^ ((lrow >> 1) & 3);   // XOR de-swizzle (64B rows)
#pragma unroll
        for (int m = 0; m < 4; ++m) {
            const int r = wr * 64 + m * 16 + lrow;
            af[m] = *reinterpret_cast<const bf16x8*>(&sA[buf][r * BK + slot * 8]);
        }
#pragma unroll
        for (int n = 0; n < 4; ++n) {
            const int r = wc * 64 + n * 16 + lrow;
            bfr[n] = *reinterpret_cast<const bf16x8*>(&sB[buf][r * BK + slot * 8]);
        }
#pragma unroll
        for (int m = 0; m < 4; ++m)
#pragma unroll
            for (int n = 0; n < 4; ++n)
                acc[m][n] = __builtin_amdgcn_mfma_f32_16x16x32_bf16(
                    af[m], bfr[n], acc[m][n], 0, 0, 0);
    };

    stage(0, 0);
    __syncthreads();
    int cur = 0;
    for (int kt = 1; kt < NKT; ++kt) {
        stage(cur ^ 1, kt);
        compute(cur);
        __syncthreads();
        cur ^= 1;
    }
    compute(cur);

    // ---- fused epilogue (block-uniform diagonal specialization) ----------
    float tsum = diag
        ? epilogue_sum<true >(acc, s_sqA, s_sqB, s_labA, s_labB, wr, wc, lrow, lk)
        : epilogue_sum<false>(acc, s_sqA, s_sqB, s_labA, s_labB, wr, wc, lrow, lk);

#pragma unroll
    for (int off = 32; off; off >>= 1) tsum += __shfl_down(tsum, off);
    if (l == 0) s_red[w] = tsum;
    __syncthreads();

    // ---- deterministic last-block reduction -------------------------------
    if (tid == 0) {
        partials[blockIdx.x] = s_red[0] + s_red[1] + s_red[2] + s_red[3];
        __threadfence();
        unsigned int tk = atomicAdd(ticket, 1u);
        s_last = (tk == NBLK - 1);
    }
    __syncthreads();
    if (s_last) {
        double s = 0.0;
        for (int i = tid; i < NBLK; i += 256)
            s += (double)atomicAdd(&partials[i], 0.0f);   // coherent RMW-load
#pragma unroll
        for (int off = 32; off; off >>= 1) s += __shfl_down(s, off);
        if (l == 0) s_redd[w] = s;
        __syncthreads();
        if (tid == 0)
            out[0] = (float)((s_redd[0] + s_redd[1] + s_redd[2] + s_redd[3])
                             / (2.0 * (double)NROWS));
    }
}

extern "C" void kernel_launch(void* const* d_in, const int* in_sizes, int n_in,
                              void* d_out, int out_size, void* d_ws,
                              size_t ws_size, hipStream_t stream) {
    const float* x      = (const float*)d_in[0];
    const int*   labels = (const int*)d_in[1];
    float*       out    = (float*)d_out;

    char* ws = (char*)d_ws;
    unsigned short* xb = (unsigned short*)ws;                       // 4 MB
    float* sq          = (float*)(ws + (size_t)NROWS * KDIM * 2);   // 16 KB
    float* partials    = (float*)(ws + (size_t)NROWS * KDIM * 2 + 16384);
    unsigned int* tick = (unsigned int*)(ws + (size_t)NROWS * KDIM * 2 + 16384 + 4096);

    prep_kernel<<<NROWS / 4, 256, 0, stream>>>(x, xb, sq, tick);
    pair_loss_kernel<<<NBLK, 256, 0, stream>>>(xb, sq, labels, partials, tick, out);
}

// Round 3
// 39.508 us; speedup vs baseline: 1.2417x; 1.0136x over previous
//
#include <hip/hip_runtime.h>
#include <hip/hip_bf16.h>

// ---------------------------------------------------------------------------
// MetricLearningLoss: total = sum_{i<j} f(||x_i-x_j||^2, same_label) / (2k)
// fp8(e4m3) MFMA gram, upper-tri 128x128 tiles, BK=64 (2x 32B panels,
// conflict-free LDS), fused epilogue + deterministic last-block reduction.
// ---------------------------------------------------------------------------

#define KDIM  512
#define NROWS 4096
#define BM    128
#define BK    64
#define NT    (NROWS / BM)        // 32
#define NBLK  (NT * (NT + 1) / 2) // 528
#define NKT   (KDIM / BK)         // 8

typedef float f32x4 __attribute__((ext_vector_type(4)));

#define GLD_LDS16(gptr, lptr)                                                  \
    __builtin_amdgcn_global_load_lds(                                          \
        (const __attribute__((address_space(1))) void*)(gptr),                 \
        (__attribute__((address_space(3))) void*)(lptr), 16, 0, 0)

// Fused: f32 -> fp8(e4m3) convert (linear layout, no swizzle needed),
// row sum-of-squares in fp32 (exact inputs), ticket zeroing.
// One wave per row (64 lanes x 8 f32 -> 8 fp8).
__global__ __launch_bounds__(256) void prep_kernel(
        const float* __restrict__ x, unsigned char* __restrict__ xb,
        float* __restrict__ sq, unsigned int* __restrict__ ticket) {
    if (blockIdx.x == 0 && threadIdx.x == 0) *ticket = 0u;
    const int w = threadIdx.x >> 6, l = threadIdx.x & 63;
    const int row = blockIdx.x * 4 + w;
    const float4* pf = reinterpret_cast<const float4*>(x + row * KDIM + l * 8);
    float4 f0 = pf[0], f1 = pf[1];
    float s = f0.x*f0.x + f0.y*f0.y + f0.z*f0.z + f0.w*f0.w
            + f1.x*f1.x + f1.y*f1.y + f1.z*f1.z + f1.w*f1.w;
#pragma unroll
    for (int off = 32; off; off >>= 1) s += __shfl_down(s, off);
    if (l == 0) sq[row] = s;

    int w0 = __builtin_amdgcn_cvt_pk_fp8_f32(f0.x, f0.y, 0, false);
    w0     = __builtin_amdgcn_cvt_pk_fp8_f32(f0.z, f0.w, w0, true);
    int w1 = __builtin_amdgcn_cvt_pk_fp8_f32(f1.x, f1.y, 0, false);
    w1     = __builtin_amdgcn_cvt_pk_fp8_f32(f1.z, f1.w, w1, true);
    *reinterpret_cast<int2*>(xb + (size_t)row * KDIM + l * 8) = make_int2(w0, w1);
}

template <bool DIAG>
__device__ __forceinline__ float epilogue_sum(
        const f32x4 (&acc)[4][4], const float* s_sqA, const float* s_sqB,
        const int* s_labA, const int* s_labB, int wr, int wc, int lrow, int lk) {
    const float c_const = (float)NROWS * 0.5f - 1.0f;               // 2047
    const float inv_zs  = (float)(1.0 / (2.0 * 4096.0 * (0.2 * 0.2)));
    const float inv_zo  = (float)(1.0 / (2.0 * 4096.0));
    const float Cs      = __logf(inv_zs);
    const float Co      = __logf(inv_zo);
    float tsum = 0.0f;
#pragma unroll
    for (int n = 0; n < 4; ++n) {
        const int   jloc = wc * 64 + n * 16 + lrow;
        const float sqj  = s_sqB[jloc];
        const int   labj = s_labB[jloc];
#pragma unroll
        for (int m = 0; m < 4; ++m) {
#pragma unroll
            for (int r = 0; r < 4; ++r) {
                const int iloc = wr * 64 + m * 16 + lk * 4 + r;
                if (!DIAG || (iloc < jloc)) {
                    float d2 = s_sqA[iloc] + sqj - 2.0f * acc[m][n][r];
                    d2 = fmaxf(d2, 1e-12f);
                    float lg   = __logf(d2);
                    bool  same = (s_labA[iloc] == labj);
                    float sc = same ? -c_const : c_const;
                    float Cx = same ? Cs : Co;
                    float Ix = same ? (0.5f * inv_zs) : (-0.5f * inv_zo);
                    tsum += sc * (lg + Cx) + d2 * Ix;
                }
            }
        }
    }
    return tsum;
}

__global__ __launch_bounds__(256, 3) void pair_loss_kernel(
        const unsigned char* __restrict__ xb,
        const float* __restrict__ sq,
        const int* __restrict__ labels,
        float* __restrict__ partials,
        unsigned int* __restrict__ ticket,
        float* __restrict__ out) {
    // [dbuf][panel(kk)][128 rows x 32 B], contiguous rows -> conflict-free b64
    __shared__ __align__(16) unsigned char sA[2][2][BM * 32];  // 16 KB
    __shared__ __align__(16) unsigned char sB[2][2][BM * 32];  // 16 KB
    __shared__ float  s_sqA[BM], s_sqB[BM];
    __shared__ int    s_labA[BM], s_labB[BM];
    __shared__ float  s_red[4];
    __shared__ double s_redd[4];
    __shared__ bool   s_last;

    const int tid = threadIdx.x;

    // XCD-chunked remap (bijective: 528 = 8 * 66), then triangular decompose
    int bid = (blockIdx.x & 7) * (NBLK / 8) + (blockIdx.x >> 3);
    int t = bid, bi = 0;
    while (t >= NT - bi) { t -= NT - bi; ++bi; }
    const int bj = bi + t;
    const int rowA0 = bi * BM, rowB0 = bj * BM;
    const bool diag = (bi == bj);

    if (tid < BM) {
        s_sqA[tid]  = sq[rowA0 + tid];
        s_labA[tid] = labels[rowA0 + tid];
    } else {
        int r = tid - BM;
        s_sqB[r]  = sq[rowB0 + r];
        s_labB[r] = labels[rowB0 + r];
    }

    const int w  = tid >> 6, l = tid & 63;
    const int wr = w >> 1,  wc = w & 1;          // wave -> 64x64 quadrant
    const int lrow = l & 15, lk = l >> 4;        // MFMA fragment coords
    const int srow = l >> 1, shalf = l & 1;      // staging coords (2 lanes/row)

    f32x4 acc[4][4];
#pragma unroll
    for (int m = 0; m < 4; ++m)
#pragma unroll
        for (int n = 0; n < 4; ++n)
            acc[m][n] = (f32x4){0.f, 0.f, 0.f, 0.f};

    // per-kt staging: 8 KB/matrix = 2 panels x 128 rows x 32 B.
    // wave w stages rows [w*32, w*32+32) of each panel (1 KB per instr).
    auto stage = [&](int buf, int kt) {
#pragma unroll
        for (int i = 0; i < 2; ++i) {            // panel index
            const int grow = w * 32 + srow;
            const size_t goff = (size_t)kt * BK + i * 32 + shalf * 16;
            const unsigned char* gA = xb + (size_t)(rowA0 + grow) * KDIM + goff;
            const unsigned char* gB = xb + (size_t)(rowB0 + grow) * KDIM + goff;
            GLD_LDS16(gA, &sA[buf][i][w * 1024]);
            GLD_LDS16(gB, &sB[buf][i][w * 1024]);
        }
    };

    auto compute = [&](int buf) {
#pragma unroll
        for (int kk = 0; kk < 2; ++kk) {         // panel = 32 k-columns
            long af[4], bfr[4];
#pragma unroll
            for (int m = 0; m < 4; ++m) {
                const int r = wr * 64 + m * 16 + lrow;
                af[m] = *reinterpret_cast<const long*>(&sA[buf][kk][r * 32 + lk * 8]);
            }
#pragma unroll
            for (int n = 0; n < 4; ++n) {
                const int r = wc * 64 + n * 16 + lrow;
                bfr[n] = *reinterpret_cast<const long*>(&sB[buf][kk][r * 32 + lk * 8]);
            }
#pragma unroll
            for (int m = 0; m < 4; ++m)
#pragma unroll
                for (int n = 0; n < 4; ++n)
                    acc[m][n] = __builtin_amdgcn_mfma_f32_16x16x32_fp8_fp8(
                        af[m], bfr[n], acc[m][n], 0, 0, 0);
        }
    };

    stage(0, 0);
    __syncthreads();
    int cur = 0;
    for (int kt = 1; kt < NKT; ++kt) {
        stage(cur ^ 1, kt);
        compute(cur);
        __syncthreads();
        cur ^= 1;
    }
    compute(cur);

    // ---- fused epilogue (block-uniform diagonal specialization) ----------
    float tsum = diag
        ? epilogue_sum<true >(acc, s_sqA, s_sqB, s_labA, s_labB, wr, wc, lrow, lk)
        : epilogue_sum<false>(acc, s_sqA, s_sqB, s_labA, s_labB, wr, wc, lrow, lk);

#pragma unroll
    for (int off = 32; off; off >>= 1) tsum += __shfl_down(tsum, off);
    if (l == 0) s_red[w] = tsum;
    __syncthreads();

    // ---- deterministic last-block reduction -------------------------------
    if (tid == 0) {
        partials[bid] = s_red[0] + s_red[1] + s_red[2] + s_red[3];
        __threadfence();
        unsigned int tk = atomicAdd(ticket, 1u);
        s_last = (tk == NBLK - 1);
    }
    __syncthreads();
    if (s_last) {
        double s = 0.0;
        for (int i = tid; i < NBLK; i += 256)
            s += (double)atomicAdd(&partials[i], 0.0f);   // coherent RMW-load
#pragma unroll
        for (int off = 32; off; off >>= 1) s += __shfl_down(s, off);
        if (l == 0) s_redd[w] = s;
        __syncthreads();
        if (tid == 0)
            out[0] = (float)((s_redd[0] + s_redd[1] + s_redd[2] + s_redd[3])
                             / (2.0 * (double)NROWS));
    }
}

extern "C" void kernel_launch(void* const* d_in, const int* in_sizes, int n_in,
                              void* d_out, int out_size, void* d_ws,
                              size_t ws_size, hipStream_t stream) {
    const float* x      = (const float*)d_in[0];
    const int*   labels = (const int*)d_in[1];
    float*       out    = (float*)d_out;

    char* ws = (char*)d_ws;
    unsigned char* xb  = (unsigned char*)ws;                    // 2 MB fp8
    float* sq          = (float*)(ws + (size_t)NROWS * KDIM);   // 16 KB
    float* partials    = (float*)(ws + (size_t)NROWS * KDIM + 16384);
    unsigned int* tick = (unsigned int*)(ws + (size_t)NROWS * KDIM + 16384 + 4096);

    prep_kernel<<<NROWS / 4, 256, 0, stream>>>(x, xb, sq, tick);
    pair_loss_kernel<<<NBLK, 256, 0, stream>>>(xb, sq, labels, partials, tick, out);
}